// Round 1
// baseline (382.953 us; speedup 1.0000x reference)
//
#include <hip/hip_runtime.h>
#include <stdint.h>

#define B_  4
#define T_  2048
#define C_  1024
#define NH_ 16
#define HD_ 64
#define BH_ (B_*NH_)   // 64
#define M_  (B_*T_)    // 8192

using f32x4  = __attribute__((ext_vector_type(4))) float;
using bf16x8 = __attribute__((ext_vector_type(8))) short;   // 8 bf16 in 4 VGPRs

__device__ __forceinline__ unsigned short f2bf(float x) {
  union { float f; uint32_t u; } v; v.f = x;
  uint32_t u = v.u;
  return (unsigned short)((u + 0x7FFFu + ((u >> 16) & 1u)) >> 16);  // RNE
}

// async global->LDS, 16B per lane. lds ptr must be wave-uniform base; HW adds lane*16.
__device__ __forceinline__ void gload16(const void* g, void* l) {
  __builtin_amdgcn_global_load_lds(
      (const __attribute__((address_space(1))) void*)g,
      (__attribute__((address_space(3))) void*)l, 16, 0, 0);
}

// ---------------- prep kernels ----------------

__global__ void k_cvt_bf16(const float* __restrict__ src,
                           unsigned short* __restrict__ dst, int n) {
  int i = (blockIdx.x * 256 + threadIdx.x) * 4;
  if (i + 3 < n) {
    float4 v = *(const float4*)(src + i);
    ushort4 o;
    o.x = f2bf(v.x); o.y = f2bf(v.y); o.z = f2bf(v.z); o.w = f2bf(v.w);
    *(ushort4*)(dst + i) = o;
  }
}

// W [K][N] f32 -> WT [N][K] bf16, 32x32 LDS tile
__global__ void k_transpose_w(const float* __restrict__ W,
                              unsigned short* __restrict__ WT, int K, int N) {
  __shared__ float tile[32][33];
  int bx = blockIdx.x, by = blockIdx.y;
  int tx = threadIdx.x, ty = threadIdx.y;   // (32,8)
  #pragma unroll
  for (int i = 0; i < 32; i += 8)
    tile[ty + i][tx] = W[(size_t)(by*32 + ty + i) * N + bx*32 + tx];
  __syncthreads();
  #pragma unroll
  for (int i = 0; i < 32; i += 8)
    WT[(size_t)(bx*32 + ty + i) * K + by*32 + tx] = f2bf(tile[tx][ty + i]);
}

__global__ void k_rope_tab(float* __restrict__ cosT, float* __restrict__ sinT) {
  int t = blockIdx.x * 8 + threadIdx.y;   // block (32,8)
  int i = threadIdx.x;                    // 0..31
  // inv_freq = 10000^(-i/32) = exp(-i*ln(10000)/32)
  float inv = expf(-(float)i * (9.210340371976184f / 32.0f));
  float f = (float)t * inv;
  cosT[t*32 + i] = cosf(f);
  sinT[t*32 + i] = sinf(f);
}

// ---------------- GEMM (128x128 tile, BK=64, 4 waves, swizzled LDS) ----------------
// A: [M][K] bf16 row-major. BT: [N][K] bf16 (B transposed, K-contiguous).
// EPI 0: qkv epilogue (bias + RoPE + scatter to Qh/Kh/VhT)
// EPI 1: proj epilogue (bias + f32 out)
template<int N, int K, int EPI>
__global__ __launch_bounds__(256)
void k_gemm(const unsigned short* __restrict__ A,
            const unsigned short* __restrict__ BT,
            const float* __restrict__ bias,
            const float* __restrict__ cosT,
            const float* __restrict__ sinT,
            unsigned short* __restrict__ Qh,
            unsigned short* __restrict__ Kh,
            unsigned short* __restrict__ VhT,
            float* __restrict__ outF) {
  __shared__ alignas(16) unsigned short As[128*64];
  __shared__ alignas(16) unsigned short Bs[128*64];
  const int tid  = threadIdx.x;
  const int lane = tid & 63;
  const int wv   = tid >> 6;
  const int wm   = wv >> 1, wn = wv & 1;
  const int m0   = blockIdx.y * 128;
  const int n0   = blockIdx.x * 128;
  const int l15  = lane & 15, l4 = lane >> 4;

  f32x4 acc[4][4] = {};

  for (int kt = 0; kt < K/64; ++kt) {
    __syncthreads();
    // stage A,B tiles: 1024 granules of 16B each; linear LDS dest,
    // inverse-swizzled global source (slot ^ (row&7)) [rule 21]
    #pragma unroll
    for (int it = 0; it < 4; ++it) {
      int idx  = it*256 + wv*64 + lane;
      int row  = idx >> 3, slot = idx & 7;
      int g    = slot ^ (row & 7);
      const unsigned short* ga = A  + ((size_t)(m0 + row) * K + kt*64 + g*8);
      const unsigned short* gb = BT + ((size_t)(n0 + row) * K + kt*64 + g*8);
      gload16(ga, (void*)(As + (it*256 + wv*64) * 8));
      gload16(gb, (void*)(Bs + (it*256 + wv*64) * 8));
    }
    __syncthreads();
    #pragma unroll
    for (int ks = 0; ks < 2; ++ks) {
      bf16x8 af[4], bfr[4];
      #pragma unroll
      for (int mi = 0; mi < 4; ++mi) {
        int r = wm*64 + mi*16 + l15;
        int g = (ks*4 + l4) ^ (r & 7);
        af[mi] = *(const bf16x8*)(As + r*64 + g*8);
      }
      #pragma unroll
      for (int ni = 0; ni < 4; ++ni) {
        int r = wn*64 + ni*16 + l15;
        int g = (ks*4 + l4) ^ (r & 7);
        bfr[ni] = *(const bf16x8*)(Bs + r*64 + g*8);
      }
      #pragma unroll
      for (int mi = 0; mi < 4; ++mi)
        #pragma unroll
        for (int ni = 0; ni < 4; ++ni)
          acc[mi][ni] = __builtin_amdgcn_mfma_f32_16x16x32_bf16(
              af[mi], bfr[ni], acc[mi][ni], 0, 0, 0);
    }
  }

  // epilogue. D layout: col = lane&15, row = (lane>>4)*4 + j  [m89/m91]
  if (EPI == 0) {
    const int ncol = n0 + wn*64;            // wave spans exactly one (part, head)
    const int part = ncol >> 10;            // 0=Q 1=K 2=V
    const int hid  = (ncol & 1023) >> 6;
    unsigned short* dstQK = (part == 0) ? Qh : Kh;
    #pragma unroll
    for (int mi = 0; mi < 4; ++mi) {
      #pragma unroll
      for (int j = 0; j < 4; ++j) {
        int row = m0 + wm*64 + mi*16 + l4*4 + j;
        int bb = row >> 11, tt = row & 2047;
        if (part < 2) {
          size_t base = ((size_t)((bb*NH_ + hid) * T_ + tt)) * HD_;
          #pragma unroll
          for (int ni = 0; ni < 2; ++ni) {
            int d = ni*16 + l15;             // d in [0,32)
            float a1 = acc[mi][ni][j]     + bias[ncol + d];
            float a2 = acc[mi][ni + 2][j] + bias[ncol + d + 32];
            float cv = cosT[tt*32 + d], sv = sinT[tt*32 + d];
            float o1 = a1*cv - a2*sv;        // rotate_half convention
            float o2 = a2*cv + a1*sv;
            if (part == 0) { o1 *= 0.125f; o2 *= 0.125f; }  // fold 1/sqrt(64), exact
            dstQK[base + d]      = f2bf(o1);
            dstQK[base + d + 32] = f2bf(o2);
          }
        } else {
          #pragma unroll
          for (int ni = 0; ni < 4; ++ni) {
            int d = ni*16 + l15;
            float av = acc[mi][ni][j] + bias[ncol + d];
            VhT[((size_t)((bb*NH_ + hid) * HD_ + d)) * T_ + tt] = f2bf(av);
          }
        }
      }
    }
  } else {
    #pragma unroll
    for (int mi = 0; mi < 4; ++mi)
      #pragma unroll
      for (int ni = 0; ni < 4; ++ni)
        #pragma unroll
        for (int j = 0; j < 4; ++j) {
          int row = m0 + wm*64 + mi*16 + l4*4 + j;
          int col = n0 + wn*64 + ni*16 + l15;
          outF[(size_t)row * N + col] = acc[mi][ni][j] + bias[col];
        }
  }
}

// ---------------- flash attention (causal), QBLK=64, KVBLK=64 ----------------
// Qh,Kh: [BH][T][64] bf16 (Q pre-scaled by 0.125); VhT: [BH][64][T] bf16.
// 4 waves x 16 q-rows. Online softmax in f32; P via per-wave swizzled LDS.
__global__ __launch_bounds__(256)
void k_attn(const unsigned short* __restrict__ Qh,
            const unsigned short* __restrict__ Kh,
            const unsigned short* __restrict__ VhT,
            unsigned short* __restrict__ Y) {
  __shared__ alignas(16) unsigned short Ks[64*64];
  __shared__ alignas(16) unsigned short Vs[64*64];   // V^T tile: [d][key]
  __shared__ alignas(16) unsigned short Ps[4*16*64];
  const int tid  = threadIdx.x;
  const int lane = tid & 63;
  const int wv   = tid >> 6;
  const int l15  = lane & 15, l4 = lane >> 4;
  const int bh   = blockIdx.y;
  const int qb   = blockIdx.x;
  const int r16  = qb*64 + wv*16;

  bf16x8 qf[2];
  {
    const unsigned short* qrow = Qh + ((size_t)(bh * T_ + r16 + l15)) * HD_;
    qf[0] = *(const bf16x8*)(qrow + l4*8);
    qf[1] = *(const bf16x8*)(qrow + 32 + l4*8);
  }

  float m_r[4], l_r[4];
  f32x4 acc_o[4] = {};
  #pragma unroll
  for (int j = 0; j < 4; ++j) { m_r[j] = -1e30f; l_r[j] = 0.f; }

  for (int jt = 0; jt <= qb; ++jt) {
    __syncthreads();
    #pragma unroll
    for (int it = 0; it < 2; ++it) {
      int idx = it*256 + wv*64 + lane;
      int row = idx >> 3, slot = idx & 7;
      int g   = slot ^ (row & 7);
      const unsigned short* gk = Kh  + ((size_t)(bh*T_ + jt*64 + row)) * HD_ + g*8;
      const unsigned short* gv = VhT + ((size_t)(bh*HD_ + row)) * T_ + jt*64 + g*8;
      gload16(gk, (void*)(Ks + (it*256 + wv*64) * 8));
      gload16(gv, (void*)(Vs + (it*256 + wv*64) * 8));
    }
    __syncthreads();

    // S = Q K^T  (16 q-rows x 64 keys)
    f32x4 sc[4] = {};
    #pragma unroll
    for (int ks = 0; ks < 2; ++ks)
      #pragma unroll
      for (int nb = 0; nb < 4; ++nb) {
        int r = nb*16 + l15;
        int g = (ks*4 + l4) ^ (r & 7);
        bf16x8 kf = *(const bf16x8*)(Ks + r*64 + g*8);
        sc[nb] = __builtin_amdgcn_mfma_f32_16x16x32_bf16(qf[ks], kf, sc[nb], 0, 0, 0);
      }

    if (jt == qb) {   // diagonal tile: causal mask
      #pragma unroll
      for (int nb = 0; nb < 4; ++nb) {
        int key = jt*64 + nb*16 + l15;
        #pragma unroll
        for (int j = 0; j < 4; ++j)
          if (key > r16 + l4*4 + j) sc[nb][j] = -1e30f;
      }
    }

    // online softmax (row = (l4*4+j); reduce across the 16 lanes holding its cols)
    float pexp[4][4];
    #pragma unroll
    for (int j = 0; j < 4; ++j) {
      float ml = fmaxf(fmaxf(sc[0][j], sc[1][j]), fmaxf(sc[2][j], sc[3][j]));
      #pragma unroll
      for (int off = 8; off > 0; off >>= 1)
        ml = fmaxf(ml, __shfl_xor(ml, off, 16));
      float mn = fmaxf(m_r[j], ml);
      float scale = __expf(m_r[j] - mn);
      m_r[j] = mn;
      float ls = 0.f;
      #pragma unroll
      for (int nb = 0; nb < 4; ++nb) {
        float p = __expf(sc[nb][j] - mn);
        pexp[nb][j] = p; ls += p;
      }
      #pragma unroll
      for (int off = 8; off > 0; off >>= 1)
        ls += __shfl_xor(ls, off, 16);
      l_r[j] = l_r[j] * scale + ls;
      #pragma unroll
      for (int nb = 0; nb < 4; ++nb) acc_o[nb][j] *= scale;
    }

    // P -> per-wave LDS (swizzled rows), then PV
    unsigned short* pb = Ps + wv*16*64;
    #pragma unroll
    for (int nb = 0; nb < 4; ++nb)
      #pragma unroll
      for (int j = 0; j < 4; ++j) {
        int r = l4*4 + j, c = nb*16 + l15;
        int g = (c >> 3) ^ (r & 7);
        pb[r*64 + g*8 + (c & 7)] = f2bf(pexp[nb][j]);
      }
    #pragma unroll
    for (int ks = 0; ks < 2; ++ks) {
      int gp = (ks*4 + l4) ^ (l15 & 7);
      bf16x8 pf = *(const bf16x8*)(pb + l15*64 + gp*8);
      #pragma unroll
      for (int nb = 0; nb < 4; ++nb) {
        int r = nb*16 + l15;
        int g = (ks*4 + l4) ^ (r & 7);
        bf16x8 vf = *(const bf16x8*)(Vs + r*64 + g*8);
        acc_o[nb] = __builtin_amdgcn_mfma_f32_16x16x32_bf16(pf, vf, acc_o[nb], 0, 0, 0);
      }
    }
  }

  // normalize + store y[b][t][h*64+d] bf16
  int b = bh >> 4, h = bh & 15;
  float rinv[4];
  #pragma unroll
  for (int j = 0; j < 4; ++j) rinv[j] = 1.0f / l_r[j];
  #pragma unroll
  for (int nb = 0; nb < 4; ++nb)
    #pragma unroll
    for (int j = 0; j < 4; ++j) {
      int tt = r16 + l4*4 + j;
      int cc = h*64 + nb*16 + l15;
      Y[((size_t)(b*T_ + tt)) * C_ + cc] = f2bf(acc_o[nb][j] * rinv[j]);
    }
}

// ---------------- host ----------------

extern "C" void kernel_launch(void* const* d_in, const int* in_sizes, int n_in,
                              void* d_out, int out_size, void* d_ws, size_t ws_size,
                              hipStream_t stream) {
  const float* x      = (const float*)d_in[0];
  const float* W_qkv  = (const float*)d_in[1];
  const float* b_qkv  = (const float*)d_in[2];
  const float* W_proj = (const float*)d_in[3];
  const float* b_proj = (const float*)d_in[4];
  float* out = (float*)d_out;

  char* ws = (char*)d_ws;
  size_t off = 0;
  auto alloc = [&](size_t bytes) {
    void* p = ws + off; off += (bytes + 255) & ~(size_t)255; return p;
  };
  unsigned short* xb     = (unsigned short*)alloc((size_t)M_ * C_ * 2);  // also reused as Y
  unsigned short* WqkvT  = (unsigned short*)alloc((size_t)3 * C_ * C_ * 2);
  unsigned short* WprojT = (unsigned short*)alloc((size_t)C_ * C_ * 2);
  unsigned short* Qh     = (unsigned short*)alloc((size_t)M_ * C_ * 2);
  unsigned short* Kh     = (unsigned short*)alloc((size_t)M_ * C_ * 2);
  unsigned short* VhT    = (unsigned short*)alloc((size_t)M_ * C_ * 2);
  float* cosT = (float*)alloc((size_t)T_ * 32 * 4);
  float* sinT = (float*)alloc((size_t)T_ * 32 * 4);
  unsigned short* Y = xb;   // xb dead after QKV GEMM; attention output aliases it

  k_cvt_bf16<<<(M_*C_/4 + 255)/256, 256, 0, stream>>>(x, xb, M_*C_);
  dim3 tb(32, 8);
  k_transpose_w<<<dim3(3*C_/32, C_/32), tb, 0, stream>>>(W_qkv, WqkvT, C_, 3*C_);
  k_transpose_w<<<dim3(C_/32,   C_/32), tb, 0, stream>>>(W_proj, WprojT, C_, C_);
  k_rope_tab<<<T_/8, tb, 0, stream>>>(cosT, sinT);

  k_gemm<3*C_, C_, 0><<<dim3(3*C_/128, M_/128), 256, 0, stream>>>(
      xb, WqkvT, b_qkv, cosT, sinT, Qh, Kh, VhT, nullptr);

  k_attn<<<dim3(T_/64, BH_), 256, 0, stream>>>(Qh, Kh, VhT, Y);

  k_gemm<C_, C_, 1><<<dim3(C_/128, M_/128), 256, 0, stream>>>(
      Y, WprojT, b_proj, nullptr, nullptr, nullptr, nullptr, nullptr, out);
}

// Round 2
// 342.690 us; speedup vs baseline: 1.1175x; 1.1175x over previous
//
#include <hip/hip_runtime.h>
#include <stdint.h>

#define B_  4
#define T_  2048
#define C_  1024
#define NH_ 16
#define HD_ 64
#define BH_ (B_*NH_)   // 64
#define M_  (B_*T_)    // 8192

using f32x4  = __attribute__((ext_vector_type(4))) float;
using bf16x8 = __attribute__((ext_vector_type(8))) short;   // 8 bf16 in 4 VGPRs

__device__ __forceinline__ unsigned short f2bf(float x) {
  union { float f; uint32_t u; } v; v.f = x;
  uint32_t u = v.u;
  return (unsigned short)((u + 0x7FFFu + ((u >> 16) & 1u)) >> 16);  // RNE
}

// async global->LDS, 16B per lane. lds ptr must be wave-uniform base; HW adds lane*16.
__device__ __forceinline__ void gload16(const void* g, void* l) {
  __builtin_amdgcn_global_load_lds(
      (const __attribute__((address_space(1))) void*)g,
      (__attribute__((address_space(3))) void*)l, 16, 0, 0);
}

// ---------------- prep kernels ----------------

__global__ void k_cvt_bf16(const float* __restrict__ src,
                           unsigned short* __restrict__ dst, int n) {
  int i = (blockIdx.x * 256 + threadIdx.x) * 4;
  if (i + 3 < n) {
    float4 v = *(const float4*)(src + i);
    ushort4 o;
    o.x = f2bf(v.x); o.y = f2bf(v.y); o.z = f2bf(v.z); o.w = f2bf(v.w);
    *(ushort4*)(dst + i) = o;
  }
}

// W [K][N] f32 -> WT [N][K] bf16, 32x32 LDS tile
__global__ void k_transpose_w(const float* __restrict__ W,
                              unsigned short* __restrict__ WT, int K, int N) {
  __shared__ float tile[32][33];
  int bx = blockIdx.x, by = blockIdx.y;
  int tx = threadIdx.x, ty = threadIdx.y;   // (32,8)
  #pragma unroll
  for (int i = 0; i < 32; i += 8)
    tile[ty + i][tx] = W[(size_t)(by*32 + ty + i) * N + bx*32 + tx];
  __syncthreads();
  #pragma unroll
  for (int i = 0; i < 32; i += 8)
    WT[(size_t)(bx*32 + ty + i) * K + by*32 + tx] = f2bf(tile[tx][ty + i]);
}

__global__ void k_rope_tab(float* __restrict__ cosT, float* __restrict__ sinT) {
  int t = blockIdx.x * 8 + threadIdx.y;   // block (32,8)
  int i = threadIdx.x;                    // 0..31
  // inv_freq = 10000^(-i/32) = exp(-i*ln(10000)/32)
  float inv = expf(-(float)i * (9.210340371976184f / 32.0f));
  float f = (float)t * inv;
  cosT[t*32 + i] = cosf(f);
  sinT[t*32 + i] = sinf(f);
}

// ---------------- GEMM (128x128 tile, BK=64, 4 waves, swizzled LDS) ----------------
// A: [M][K] bf16 row-major. BT: [N][K] bf16 (B transposed, K-contiguous).
// EPI 0: qkv epilogue (bias + RoPE + scatter to Qh/Kh/VhT)
// EPI 1: proj epilogue (bias + f32 out)
template<int N, int K, int EPI>
__global__ __launch_bounds__(256)
void k_gemm(const unsigned short* __restrict__ A,
            const unsigned short* __restrict__ BT,
            const float* __restrict__ bias,
            const float* __restrict__ cosT,
            const float* __restrict__ sinT,
            unsigned short* __restrict__ Qh,
            unsigned short* __restrict__ Kh,
            unsigned short* __restrict__ VhT,
            float* __restrict__ outF) {
  __shared__ alignas(16) unsigned short As[128*64];
  __shared__ alignas(16) unsigned short Bs[128*64];
  const int tid  = threadIdx.x;
  const int lane = tid & 63;
  const int wv   = tid >> 6;
  const int wm   = wv >> 1, wn = wv & 1;
  const int m0   = blockIdx.y * 128;
  const int n0   = blockIdx.x * 128;
  const int l15  = lane & 15, l4 = lane >> 4;

  f32x4 acc[4][4] = {};

  for (int kt = 0; kt < K/64; ++kt) {
    __syncthreads();
    // stage A,B tiles: 1024 granules of 16B each; linear LDS dest,
    // inverse-swizzled global source (slot ^ (row&7)) [rule 21]
    #pragma unroll
    for (int it = 0; it < 4; ++it) {
      int idx  = it*256 + wv*64 + lane;
      int row  = idx >> 3, slot = idx & 7;
      int g    = slot ^ (row & 7);
      const unsigned short* ga = A  + ((size_t)(m0 + row) * K + kt*64 + g*8);
      const unsigned short* gb = BT + ((size_t)(n0 + row) * K + kt*64 + g*8);
      gload16(ga, (void*)(As + (it*256 + wv*64) * 8));
      gload16(gb, (void*)(Bs + (it*256 + wv*64) * 8));
    }
    __syncthreads();
    #pragma unroll
    for (int ks = 0; ks < 2; ++ks) {
      bf16x8 af[4], bfr[4];
      #pragma unroll
      for (int mi = 0; mi < 4; ++mi) {
        int r = wm*64 + mi*16 + l15;
        int g = (ks*4 + l4) ^ (r & 7);
        af[mi] = *(const bf16x8*)(As + r*64 + g*8);
      }
      #pragma unroll
      for (int ni = 0; ni < 4; ++ni) {
        int r = wn*64 + ni*16 + l15;
        int g = (ks*4 + l4) ^ (r & 7);
        bfr[ni] = *(const bf16x8*)(Bs + r*64 + g*8);
      }
      #pragma unroll
      for (int mi = 0; mi < 4; ++mi)
        #pragma unroll
        for (int ni = 0; ni < 4; ++ni)
          acc[mi][ni] = __builtin_amdgcn_mfma_f32_16x16x32_bf16(
              af[mi], bfr[ni], acc[mi][ni], 0, 0, 0);
    }
  }

  // epilogue. D layout: col = lane&15, row = (lane>>4)*4 + j  [m89/m91]
  if (EPI == 0) {
    const int ncol = n0 + wn*64;            // wave spans exactly one (part, head)
    const int part = ncol >> 10;            // 0=Q 1=K 2=V
    const int hid  = (ncol & 1023) >> 6;
    unsigned short* dstQK = (part == 0) ? Qh : Kh;
    #pragma unroll
    for (int mi = 0; mi < 4; ++mi) {
      #pragma unroll
      for (int j = 0; j < 4; ++j) {
        int row = m0 + wm*64 + mi*16 + l4*4 + j;
        int bb = row >> 11, tt = row & 2047;
        if (part < 2) {
          size_t base = ((size_t)((bb*NH_ + hid) * T_ + tt)) * HD_;
          #pragma unroll
          for (int ni = 0; ni < 2; ++ni) {
            int d = ni*16 + l15;             // d in [0,32)
            float a1 = acc[mi][ni][j]     + bias[ncol + d];
            float a2 = acc[mi][ni + 2][j] + bias[ncol + d + 32];
            float cv = cosT[tt*32 + d], sv = sinT[tt*32 + d];
            float o1 = a1*cv - a2*sv;        // rotate_half convention
            float o2 = a2*cv + a1*sv;
            if (part == 0) { o1 *= 0.125f; o2 *= 0.125f; }  // fold 1/sqrt(64), exact
            dstQK[base + d]      = f2bf(o1);
            dstQK[base + d + 32] = f2bf(o2);
          }
        } else {
          #pragma unroll
          for (int ni = 0; ni < 4; ++ni) {
            int d = ni*16 + l15;
            float av = acc[mi][ni][j] + bias[ncol + d];
            VhT[((size_t)((bb*NH_ + hid) * HD_ + d)) * T_ + tt] = f2bf(av);
          }
        }
      }
    }
  } else {
    #pragma unroll
    for (int mi = 0; mi < 4; ++mi)
      #pragma unroll
      for (int ni = 0; ni < 4; ++ni)
        #pragma unroll
        for (int j = 0; j < 4; ++j) {
          int row = m0 + wm*64 + mi*16 + l4*4 + j;
          int col = n0 + wn*64 + ni*16 + l15;
          outF[(size_t)row * N + col] = acc[mi][ni][j] + bias[col];
        }
  }
}

// ---------------- flash attention (causal), QBLK=128, KVBLK=64, dbuf+counted vmcnt ----
// Qh,Kh: [BH][T][64] bf16 (Q pre-scaled by 0.125); VhT: [BH][64][T] bf16.
// 4 waves x 32 q-rows. Online softmax in f32; P via per-wave swizzled LDS.
__global__ __launch_bounds__(256, 2)
void k_attn(const unsigned short* __restrict__ Qh,
            const unsigned short* __restrict__ Kh,
            const unsigned short* __restrict__ VhT,
            unsigned short* __restrict__ Y) {
  __shared__ alignas(16) unsigned short Ks[2][64*64];
  __shared__ alignas(16) unsigned short Vs[2][64*64];   // V^T tile: [d][key]
  __shared__ alignas(16) unsigned short Ps[4*32*64];
  const int tid  = threadIdx.x;
  const int lane = tid & 63;
  const int wv   = tid >> 6;
  const int l15  = lane & 15, l4 = lane >> 4;
  const int bh   = blockIdx.y;
  const int qb   = (gridDim.x - 1) - blockIdx.x;   // longest blocks dispatch first
  const int r32  = qb*128 + wv*32;                  // wave's first q-row
  const int nt   = 2*qb + 2;                        // kv tiles to visit

  // Q fragments in registers: [row-block][k-chunk]
  bf16x8 qf[2][2];
  #pragma unroll
  for (int mi = 0; mi < 2; ++mi)
    #pragma unroll
    for (int ks = 0; ks < 2; ++ks)
      qf[mi][ks] = *(const bf16x8*)(
          Qh + ((size_t)(bh*T_ + r32 + mi*16 + l15))*HD_ + ks*32 + l4*8);

  float m_r[2][4], l_r[2][4];
  f32x4 acc_o[2][4] = {};
  #pragma unroll
  for (int mi = 0; mi < 2; ++mi)
    #pragma unroll
    for (int j = 0; j < 4; ++j) { m_r[mi][j] = -1e30f; l_r[mi][j] = 0.f; }

  // stage kv tile jt into buffer `buf` (4 gload16 per wave: 2 K + 2 V)
  auto stage = [&](int buf, int jt) {
    #pragma unroll
    for (int it = 0; it < 2; ++it) {
      int idx = it*256 + wv*64 + lane;
      int row = idx >> 3, slot = idx & 7;
      int g   = slot ^ (row & 7);
      gload16(Kh  + ((size_t)(bh*T_ + jt*64 + row))*HD_ + g*8,
              (void*)(Ks[buf] + (it*256 + wv*64)*8));
      gload16(VhT + ((size_t)(bh*HD_ + row))*T_ + jt*64 + g*8,
              (void*)(Vs[buf] + (it*256 + wv*64)*8));
    }
  };

  unsigned short* pb = Ps + wv*32*64;
  stage(0, 0);
  int cur = 0;

  for (int jt = 0; jt < nt; ++jt) {
    if (jt + 1 < nt) {
      stage(cur ^ 1, jt + 1);                       // prefetch next tile
      asm volatile("s_waitcnt vmcnt(4)" ::: "memory");  // cur's 4 loads done; prefetch stays in flight
    } else {
      asm volatile("s_waitcnt vmcnt(0)" ::: "memory");
    }
    __builtin_amdgcn_s_barrier();
    asm volatile("" ::: "memory");                  // pin ds_reads below the barrier

    // skip tiles where every key > every row of this wave (fully masked) — wave-uniform
    if (jt*64 <= r32 + 31) {
      // S = Q K^T  (32 q-rows x 64 keys)
      f32x4 sc[2][4] = {};
      #pragma unroll
      for (int ks = 0; ks < 2; ++ks)
        #pragma unroll
        for (int nb = 0; nb < 4; ++nb) {
          int r = nb*16 + l15;
          int g = (ks*4 + l4) ^ (r & 7);
          bf16x8 kf = *(const bf16x8*)(Ks[cur] + r*64 + g*8);
          #pragma unroll
          for (int mi = 0; mi < 2; ++mi)
            sc[mi][nb] = __builtin_amdgcn_mfma_f32_16x16x32_bf16(
                qf[mi][ks], kf, sc[mi][nb], 0, 0, 0);
        }

      if (jt*64 + 63 > r32) {   // tile overlaps diagonal: causal mask
        #pragma unroll
        for (int mi = 0; mi < 2; ++mi)
          #pragma unroll
          for (int nb = 0; nb < 4; ++nb) {
            int key = jt*64 + nb*16 + l15;
            #pragma unroll
            for (int j = 0; j < 4; ++j)
              if (key > r32 + mi*16 + l4*4 + j) sc[mi][nb][j] = -1e30f;
          }
      }

      // online softmax per q-row (16 lanes hold its 64 cols, 4 each)
      float pexp[2][4][4];
      #pragma unroll
      for (int mi = 0; mi < 2; ++mi)
        #pragma unroll
        for (int j = 0; j < 4; ++j) {
          float ml = fmaxf(fmaxf(sc[mi][0][j], sc[mi][1][j]),
                           fmaxf(sc[mi][2][j], sc[mi][3][j]));
          #pragma unroll
          for (int off = 8; off > 0; off >>= 1)
            ml = fmaxf(ml, __shfl_xor(ml, off, 16));
          float mn = fmaxf(m_r[mi][j], ml);
          float scale = __expf(m_r[mi][j] - mn);
          m_r[mi][j] = mn;
          float ls = 0.f;
          #pragma unroll
          for (int nb = 0; nb < 4; ++nb) {
            float p = __expf(sc[mi][nb][j] - mn);
            pexp[mi][nb][j] = p; ls += p;
          }
          #pragma unroll
          for (int off = 8; off > 0; off >>= 1)
            ls += __shfl_xor(ls, off, 16);
          l_r[mi][j] = l_r[mi][j] * scale + ls;
          #pragma unroll
          for (int nb = 0; nb < 4; ++nb) acc_o[mi][nb][j] *= scale;
        }

      // P -> per-wave LDS (swizzled rows), then PV
      #pragma unroll
      for (int mi = 0; mi < 2; ++mi)
        #pragma unroll
        for (int nb = 0; nb < 4; ++nb)
          #pragma unroll
          for (int j = 0; j < 4; ++j) {
            int r = mi*16 + l4*4 + j, c = nb*16 + l15;
            int g = (c >> 3) ^ (r & 7);
            pb[r*64 + g*8 + (c & 7)] = f2bf(pexp[mi][nb][j]);
          }
      #pragma unroll
      for (int ks = 0; ks < 2; ++ks) {
        bf16x8 pf[2];
        #pragma unroll
        for (int mi = 0; mi < 2; ++mi) {
          int rr = mi*16 + l15;
          int gp = (ks*4 + l4) ^ (rr & 7);
          pf[mi] = *(const bf16x8*)(pb + rr*64 + gp*8);
        }
        #pragma unroll
        for (int nb = 0; nb < 4; ++nb) {
          int r = nb*16 + l15;
          int g = (ks*4 + l4) ^ (r & 7);
          bf16x8 vf = *(const bf16x8*)(Vs[cur] + r*64 + g*8);
          #pragma unroll
          for (int mi = 0; mi < 2; ++mi)
            acc_o[mi][nb] = __builtin_amdgcn_mfma_f32_16x16x32_bf16(
                pf[mi], vf, acc_o[mi][nb], 0, 0, 0);
        }
      }
    }

    __syncthreads();   // buffer-reuse protection; prefetch has had whole compute to land
    cur ^= 1;
  }

  // normalize + store y[b][t][h*64+d] bf16
  int b = bh >> 4, h = bh & 15;
  float rinv[2][4];
  #pragma unroll
  for (int mi = 0; mi < 2; ++mi)
    #pragma unroll
    for (int j = 0; j < 4; ++j) rinv[mi][j] = 1.0f / l_r[mi][j];
  #pragma unroll
  for (int mi = 0; mi < 2; ++mi)
    #pragma unroll
    for (int nb = 0; nb < 4; ++nb)
      #pragma unroll
      for (int j = 0; j < 4; ++j) {
        int tt = r32 + mi*16 + l4*4 + j;
        int cc = h*64 + nb*16 + l15;
        Y[((size_t)(b*T_ + tt)) * C_ + cc] = f2bf(acc_o[mi][nb][j] * rinv[mi][j]);
      }
}

// ---------------- host ----------------

extern "C" void kernel_launch(void* const* d_in, const int* in_sizes, int n_in,
                              void* d_out, int out_size, void* d_ws, size_t ws_size,
                              hipStream_t stream) {
  const float* x      = (const float*)d_in[0];
  const float* W_qkv  = (const float*)d_in[1];
  const float* b_qkv  = (const float*)d_in[2];
  const float* W_proj = (const float*)d_in[3];
  const float* b_proj = (const float*)d_in[4];
  float* out = (float*)d_out;

  char* ws = (char*)d_ws;
  size_t off = 0;
  auto alloc = [&](size_t bytes) {
    void* p = ws + off; off += (bytes + 255) & ~(size_t)255; return p;
  };
  unsigned short* xb     = (unsigned short*)alloc((size_t)M_ * C_ * 2);  // also reused as Y
  unsigned short* WqkvT  = (unsigned short*)alloc((size_t)3 * C_ * C_ * 2);
  unsigned short* WprojT = (unsigned short*)alloc((size_t)C_ * C_ * 2);
  unsigned short* Qh     = (unsigned short*)alloc((size_t)M_ * C_ * 2);
  unsigned short* Kh     = (unsigned short*)alloc((size_t)M_ * C_ * 2);
  unsigned short* VhT    = (unsigned short*)alloc((size_t)M_ * C_ * 2);
  float* cosT = (float*)alloc((size_t)T_ * 32 * 4);
  float* sinT = (float*)alloc((size_t)T_ * 32 * 4);
  unsigned short* Y = xb;   // xb dead after QKV GEMM; attention output aliases it

  k_cvt_bf16<<<(M_*C_/4 + 255)/256, 256, 0, stream>>>(x, xb, M_*C_);
  dim3 tb(32, 8);
  k_transpose_w<<<dim3(3*C_/32, C_/32), tb, 0, stream>>>(W_qkv, WqkvT, C_, 3*C_);
  k_transpose_w<<<dim3(C_/32,   C_/32), tb, 0, stream>>>(W_proj, WprojT, C_, C_);
  k_rope_tab<<<T_/8, tb, 0, stream>>>(cosT, sinT);

  k_gemm<3*C_, C_, 0><<<dim3(3*C_/128, M_/128), 256, 0, stream>>>(
      xb, WqkvT, b_qkv, cosT, sinT, Qh, Kh, VhT, nullptr);

  k_attn<<<dim3(T_/128, BH_), 256, 0, stream>>>(Qh, Kh, VhT, Y);

  k_gemm<C_, C_, 1><<<dim3(C_/128, M_/128), 256, 0, stream>>>(
      Y, WprojT, b_proj, nullptr, nullptr, nullptr, nullptr, nullptr, out);
}

// Round 4
// 280.286 us; speedup vs baseline: 1.3663x; 1.2226x over previous
//
#include <hip/hip_runtime.h>
#include <stdint.h>

#define B_  4
#define T_  2048
#define C_  1024
#define NH_ 16
#define HD_ 64
#define BH_ (B_*NH_)   // 64
#define M_  (B_*T_)    // 8192

using f32x4  = __attribute__((ext_vector_type(4))) float;
using f32x16 = __attribute__((ext_vector_type(16))) float;
using bf16x8 = __attribute__((ext_vector_type(8))) short;   // 8 bf16 in 4 VGPRs

__device__ __forceinline__ unsigned short f2bf(float x) {
  union { float f; uint32_t u; } v; v.f = x;
  uint32_t u = v.u;
  return (unsigned short)((u + 0x7FFFu + ((u >> 16) & 1u)) >> 16);  // RNE
}

// packed f32x2 -> bf16x2 in one dword (lo=cvt(a), hi=cvt(b))
__device__ __forceinline__ uint32_t cvtpk(float a, float b) {
  uint32_t r;
  asm("v_cvt_pk_bf16_f32 %0, %1, %2" : "=v"(r) : "v"(a), "v"(b));
  return r;
}

// async global->LDS, 16B per lane. lds ptr must be wave-uniform base; HW adds lane*16.
__device__ __forceinline__ void gload16(const void* g, void* l) {
  __builtin_amdgcn_global_load_lds(
      (const __attribute__((address_space(1))) void*)g,
      (__attribute__((address_space(3))) void*)l, 16, 0, 0);
}

// ---------------- prep kernels ----------------

__global__ void k_cvt_bf16(const float* __restrict__ src,
                           unsigned short* __restrict__ dst, int n) {
  int i = (blockIdx.x * 256 + threadIdx.x) * 4;
  if (i + 3 < n) {
    float4 v = *(const float4*)(src + i);
    ushort4 o;
    o.x = f2bf(v.x); o.y = f2bf(v.y); o.z = f2bf(v.z); o.w = f2bf(v.w);
    *(ushort4*)(dst + i) = o;
  }
}

// W [K][N] f32 -> WT [N][K] bf16, 32x32 LDS tile
__global__ void k_transpose_w(const float* __restrict__ W,
                              unsigned short* __restrict__ WT, int K, int N) {
  __shared__ float tile[32][33];
  int bx = blockIdx.x, by = blockIdx.y;
  int tx = threadIdx.x, ty = threadIdx.y;   // (32,8)
  #pragma unroll
  for (int i = 0; i < 32; i += 8)
    tile[ty + i][tx] = W[(size_t)(by*32 + ty + i) * N + bx*32 + tx];
  __syncthreads();
  #pragma unroll
  for (int i = 0; i < 32; i += 8)
    WT[(size_t)(bx*32 + ty + i) * K + by*32 + tx] = f2bf(tile[tx][ty + i]);
}

__global__ void k_rope_tab(float* __restrict__ cosT, float* __restrict__ sinT) {
  int t = blockIdx.x * 8 + threadIdx.y;   // block (32,8)
  int i = threadIdx.x;                    // 0..31
  float inv = expf(-(float)i * (9.210340371976184f / 32.0f));
  float f = (float)t * inv;
  cosT[t*32 + i] = cosf(f);
  sinT[t*32 + i] = sinf(f);
}

// ---------------- GEMM (128x128 tile, BK=64, 4 waves, swizzled LDS) ----------------
template<int N, int K, int EPI>
__global__ __launch_bounds__(256)
void k_gemm(const unsigned short* __restrict__ A,
            const unsigned short* __restrict__ BT,
            const float* __restrict__ bias,
            const float* __restrict__ cosT,
            const float* __restrict__ sinT,
            unsigned short* __restrict__ Qh,
            unsigned short* __restrict__ Kh,
            unsigned short* __restrict__ VhT,
            float* __restrict__ outF) {
  __shared__ alignas(16) unsigned short As[128*64];
  __shared__ alignas(16) unsigned short Bs[128*64];
  const int tid  = threadIdx.x;
  const int lane = tid & 63;
  const int wv   = tid >> 6;
  const int wm   = wv >> 1, wn = wv & 1;
  const int m0   = blockIdx.y * 128;
  const int n0   = blockIdx.x * 128;
  const int l15  = lane & 15, l4 = lane >> 4;

  f32x4 acc[4][4] = {};

  for (int kt = 0; kt < K/64; ++kt) {
    __syncthreads();
    #pragma unroll
    for (int it = 0; it < 4; ++it) {
      int idx  = it*256 + wv*64 + lane;
      int row  = idx >> 3, slot = idx & 7;
      int g    = slot ^ (row & 7);
      const unsigned short* ga = A  + ((size_t)(m0 + row) * K + kt*64 + g*8);
      const unsigned short* gb = BT + ((size_t)(n0 + row) * K + kt*64 + g*8);
      gload16(ga, (void*)(As + (it*256 + wv*64) * 8));
      gload16(gb, (void*)(Bs + (it*256 + wv*64) * 8));
    }
    __syncthreads();
    #pragma unroll
    for (int ks = 0; ks < 2; ++ks) {
      bf16x8 af[4], bfr[4];
      #pragma unroll
      for (int mi = 0; mi < 4; ++mi) {
        int r = wm*64 + mi*16 + l15;
        int g = (ks*4 + l4) ^ (r & 7);
        af[mi] = *(const bf16x8*)(As + r*64 + g*8);
      }
      #pragma unroll
      for (int ni = 0; ni < 4; ++ni) {
        int r = wn*64 + ni*16 + l15;
        int g = (ks*4 + l4) ^ (r & 7);
        bfr[ni] = *(const bf16x8*)(Bs + r*64 + g*8);
      }
      #pragma unroll
      for (int mi = 0; mi < 4; ++mi)
        #pragma unroll
        for (int ni = 0; ni < 4; ++ni)
          acc[mi][ni] = __builtin_amdgcn_mfma_f32_16x16x32_bf16(
              af[mi], bfr[ni], acc[mi][ni], 0, 0, 0);
    }
  }

  if (EPI == 0) {
    const int ncol = n0 + wn*64;            // wave spans exactly one (part, head)
    const int part = ncol >> 10;            // 0=Q 1=K 2=V
    const int hid  = (ncol & 1023) >> 6;
    unsigned short* dstQK = (part == 0) ? Qh : Kh;
    #pragma unroll
    for (int mi = 0; mi < 4; ++mi) {
      #pragma unroll
      for (int j = 0; j < 4; ++j) {
        int row = m0 + wm*64 + mi*16 + l4*4 + j;
        int bb = row >> 11, tt = row & 2047;
        if (part < 2) {
          size_t base = ((size_t)((bb*NH_ + hid) * T_ + tt)) * HD_;
          #pragma unroll
          for (int ni = 0; ni < 2; ++ni) {
            int d = ni*16 + l15;
            float a1 = acc[mi][ni][j]     + bias[ncol + d];
            float a2 = acc[mi][ni + 2][j] + bias[ncol + d + 32];
            float cv = cosT[tt*32 + d], sv = sinT[tt*32 + d];
            float o1 = a1*cv - a2*sv;
            float o2 = a2*cv + a1*sv;
            if (part == 0) { o1 *= 0.125f; o2 *= 0.125f; }
            dstQK[base + d]      = f2bf(o1);
            dstQK[base + d + 32] = f2bf(o2);
          }
        } else {
          #pragma unroll
          for (int ni = 0; ni < 4; ++ni) {
            int d = ni*16 + l15;
            float av = acc[mi][ni][j] + bias[ncol + d];
            VhT[((size_t)((bb*NH_ + hid) * HD_ + d)) * T_ + tt] = f2bf(av);
          }
        }
      }
    }
  } else {
    #pragma unroll
    for (int mi = 0; mi < 4; ++mi)
      #pragma unroll
      for (int ni = 0; ni < 4; ++ni)
        #pragma unroll
        for (int j = 0; j < 4; ++j) {
          int row = m0 + wm*64 + mi*16 + l4*4 + j;
          int col = n0 + wn*64 + ni*16 + l15;
          outF[(size_t)row * N + col] = acc[mi][ni][j] + bias[col];
        }
  }
}

// ---------------- flash attention (causal), 32x32 MFMA, swapped QK^T ----------------
// Qh,Kh: [BH][T][64] bf16 (Q pre-scaled by 0.125); VhT: [BH][64][T] bf16.
// QBLK=128, 4 waves x 32 q-rows, KVBLK=64. Lane l owns q-row (l&31): m,l scalar/lane.
// S^T via mfma(K,Q): D col=lane&31=q, row(key)=(reg&3)+8*(reg>>2)+4*(lane>>5).
// PV via mfma(V^T, P): D col=lane&31=q (lane-local!), reg pattern = d.
// P stays in registers: cvt_pk + shfl_xor(32) builds the P B-frags. No P LDS.
__global__ __launch_bounds__(256, 3)
void k_attn(const unsigned short* __restrict__ Qh,
            const unsigned short* __restrict__ Kh,
            const unsigned short* __restrict__ VhT,
            unsigned short* __restrict__ Y) {
  __shared__ alignas(16) unsigned short Ks[2][64*64];   // [key][d], XOR-swizzled 16B granules
  __shared__ alignas(16) unsigned short Vs[2][64*64];   // [d][key], XOR-swizzled
  const int tid  = threadIdx.x;
  const int lane = tid & 63;
  const int wv   = tid >> 6;
  const int l31  = lane & 31;
  const int h    = lane >> 5;
  const int bh   = blockIdx.y;
  const int qb   = (gridDim.x - 1) - blockIdx.x;   // longest blocks dispatch first
  const int r32  = qb*128 + wv*32;                  // wave's first q-row
  const int nt   = 2*qb + 2;
  const int qg   = r32 + l31;                       // this lane's q-row (global)

  // Q B-frags: qf[i] = Q[qg][d = i*16 + h*8 + e]
  bf16x8 qf[4];
  #pragma unroll
  for (int i = 0; i < 4; ++i)
    qf[i] = *(const bf16x8*)(Qh + ((size_t)(bh*T_ + qg))*HD_ + i*16 + h*8);

  float m_r = -1e30f, l_r = 0.f;
  f32x16 o[2] = {};   // o[dblk][r]: O[q = qg][d = dblk*32 + (r&3)+8*(r>>2)+4*h]

  auto stage = [&](int buf, int jt) {
    #pragma unroll
    for (int it = 0; it < 2; ++it) {
      int idx = it*256 + wv*64 + lane;
      int row = idx >> 3, slot = idx & 7;
      int g   = slot ^ (row & 7);
      gload16(Kh  + ((size_t)(bh*T_ + jt*64 + row))*HD_ + g*8,
              (void*)(Ks[buf] + (it*256 + wv*64)*8));
      gload16(VhT + ((size_t)(bh*HD_ + row))*T_ + jt*64 + g*8,
              (void*)(Vs[buf] + (it*256 + wv*64)*8));
    }
  };

  stage(0, 0);
  int cur = 0;

  for (int jt = 0; jt < nt; ++jt) {
    if (jt + 1 < nt) {
      stage(cur ^ 1, jt + 1);
      asm volatile("s_waitcnt vmcnt(4)" ::: "memory");
    } else {
      asm volatile("s_waitcnt vmcnt(0)" ::: "memory");
    }
    __builtin_amdgcn_s_barrier();
    asm volatile("" ::: "memory");

    if (jt*64 <= r32 + 31) {     // wave-uniform skip of fully-masked tiles
      // S^T tiles: s[kb][r] = S[key = jt*64+kb*32+(r&3)+8*(r>>2)+4*h][q = qg]
      f32x16 s[2] = {f32x16{0}, f32x16{0}};
      __builtin_amdgcn_s_setprio(1);
      #pragma unroll
      for (int kb = 0; kb < 2; ++kb)
        #pragma unroll
        for (int i = 0; i < 4; ++i) {
          int r = kb*32 + l31;
          int g = (2*i + h) ^ (r & 7);
          bf16x8 kf = *(const bf16x8*)(Ks[cur] + r*64 + g*8);
          s[kb] = __builtin_amdgcn_mfma_f32_32x32x16_bf16(kf, qf[i], s[kb], 0, 0, 0);
        }
      __builtin_amdgcn_s_setprio(0);

      // extract + causal mask (diagonal tile only)
      float p[2][16];
      const bool diag = (jt + 1)*64 > r32;
      #pragma unroll
      for (int kb = 0; kb < 2; ++kb)
        #pragma unroll
        for (int r = 0; r < 16; ++r) {
          float v = s[kb][r];
          if (diag) {
            int key = jt*64 + kb*32 + (r & 3) + 8*(r >> 2) + 4*h;
            v = (key > qg) ? -1e30f : v;
          }
          p[kb][r] = v;
        }

      // row max: in-lane tree + one cross-half swap
      float mx[16];
      #pragma unroll
      for (int r = 0; r < 16; ++r) mx[r] = fmaxf(p[0][r], p[1][r]);
      #pragma unroll
      for (int st = 8; st > 0; st >>= 1)
        #pragma unroll
        for (int r = 0; r < 8; ++r)
          if (r < st) mx[r] = fmaxf(mx[r], mx[r + st]);
      float tm = fmaxf(mx[0], __shfl_xor(mx[0], 32));

      float mn = fmaxf(m_r, tm);
      float scale = __expf(m_r - mn);
      m_r = mn;

      #pragma unroll
      for (int kb = 0; kb < 2; ++kb)
        #pragma unroll
        for (int r = 0; r < 16; ++r)
          p[kb][r] = __expf(p[kb][r] - mn);

      float sm[16];
      #pragma unroll
      for (int r = 0; r < 16; ++r) sm[r] = p[0][r] + p[1][r];
      #pragma unroll
      for (int st = 8; st > 0; st >>= 1)
        #pragma unroll
        for (int r = 0; r < 8; ++r)
          if (r < st) sm[r] += sm[r + st];
      float ls = sm[0] + __shfl_xor(sm[0], 32);
      l_r = l_r * scale + ls;

      // rescale O — lane-local q now, scale applies directly
      #pragma unroll
      for (int dblk = 0; dblk < 2; ++dblk)
        #pragma unroll
        for (int r = 0; r < 16; ++r)
          o[dblk][r] *= scale;

      // PV per key-block: build P B-frags from p via cvt_pk + cross-half swap.
      // B-frag koff: lane provides P[key = kb*32+koff*16+h*8+e][q = l31].
      #pragma unroll
      for (int kb = 0; kb < 2; ++kb) {
        uint32_t a01 = cvtpk(p[kb][0],  p[kb][1]);
        uint32_t a23 = cvtpk(p[kb][2],  p[kb][3]);
        uint32_t a45 = cvtpk(p[kb][4],  p[kb][5]);
        uint32_t a67 = cvtpk(p[kb][6],  p[kb][7]);
        uint32_t b01 = cvtpk(p[kb][8],  p[kb][9]);
        uint32_t b23 = cvtpk(p[kb][10], p[kb][11]);
        uint32_t b45 = cvtpk(p[kb][12], p[kb][13]);
        uint32_t b67 = cvtpk(p[kb][14], p[kb][15]);
        uint32_t xa01 = __shfl_xor(a01, 32), xa23 = __shfl_xor(a23, 32);
        uint32_t xa45 = __shfl_xor(a45, 32), xa67 = __shfl_xor(a67, 32);
        uint32_t xb01 = __shfl_xor(b01, 32), xb23 = __shfl_xor(b23, 32);
        uint32_t xb45 = __shfl_xor(b45, 32), xb67 = __shfl_xor(b67, 32);
        union { bf16x8 v; uint32_t d[4]; } f0, f1;
        f0.d[0] = h ? xa45 : a01;  f0.d[1] = h ? xa67 : a23;
        f0.d[2] = h ? a45 : xa01;  f0.d[3] = h ? a67 : xa23;
        f1.d[0] = h ? xb45 : b01;  f1.d[1] = h ? xb67 : b23;
        f1.d[2] = h ? b45 : xb01;  f1.d[3] = h ? b67 : xb23;

        __builtin_amdgcn_s_setprio(1);
        #pragma unroll
        for (int koff = 0; koff < 2; ++koff) {
          bf16x8 pf = koff ? f1.v : f0.v;
          #pragma unroll
          for (int dblk = 0; dblk < 2; ++dblk) {
            int rv = dblk*32 + l31;
            int gv = (kb*4 + koff*2 + h) ^ (rv & 7);
            bf16x8 vf = *(const bf16x8*)(Vs[cur] + rv*64 + gv*8);
            // A = V^T (row=d, lane-local l31), B = P (col=q, lane-local l31)
            o[dblk] = __builtin_amdgcn_mfma_f32_32x32x16_bf16(vf, pf, o[dblk], 0, 0, 0);
          }
        }
        __builtin_amdgcn_s_setprio(0);
      }
    }

    __syncthreads();
    cur ^= 1;
  }

  // epilogue: lane-local normalize, packed ushort4 stores
  // o[dblk][g2*4+j] -> d = dblk*32 + 8*g2 + 4*h + j  (4 consecutive d per reg-quad)
  int b = bh >> 4, hd = bh & 15;
  float rinv = 1.0f / l_r;
  unsigned short* yrow = Y + ((size_t)(b*T_ + r32 + l31))*C_ + hd*64;
  #pragma unroll
  for (int dblk = 0; dblk < 2; ++dblk)
    #pragma unroll
    for (int g2 = 0; g2 < 4; ++g2) {
      ushort4 o4;
      o4.x = f2bf(o[dblk][g2*4 + 0] * rinv);
      o4.y = f2bf(o[dblk][g2*4 + 1] * rinv);
      o4.z = f2bf(o[dblk][g2*4 + 2] * rinv);
      o4.w = f2bf(o[dblk][g2*4 + 3] * rinv);
      *(ushort4*)(yrow + dblk*32 + g2*8 + 4*h) = o4;
    }
}

// ---------------- host ----------------

extern "C" void kernel_launch(void* const* d_in, const int* in_sizes, int n_in,
                              void* d_out, int out_size, void* d_ws, size_t ws_size,
                              hipStream_t stream) {
  const float* x      = (const float*)d_in[0];
  const float* W_qkv  = (const float*)d_in[1];
  const float* b_qkv  = (const float*)d_in[2];
  const float* W_proj = (const float*)d_in[3];
  const float* b_proj = (const float*)d_in[4];
  float* out = (float*)d_out;

  char* ws = (char*)d_ws;
  size_t off = 0;
  auto alloc = [&](size_t bytes) {
    void* p = ws + off; off += (bytes + 255) & ~(size_t)255; return p;
  };
  unsigned short* xb     = (unsigned short*)alloc((size_t)M_ * C_ * 2);  // also reused as Y
  unsigned short* WqkvT  = (unsigned short*)alloc((size_t)3 * C_ * C_ * 2);
  unsigned short* WprojT = (unsigned short*)alloc((size_t)C_ * C_ * 2);
  unsigned short* Qh     = (unsigned short*)alloc((size_t)M_ * C_ * 2);
  unsigned short* Kh     = (unsigned short*)alloc((size_t)M_ * C_ * 2);
  unsigned short* VhT    = (unsigned short*)alloc((size_t)M_ * C_ * 2);
  float* cosT = (float*)alloc((size_t)T_ * 32 * 4);
  float* sinT = (float*)alloc((size_t)T_ * 32 * 4);
  unsigned short* Y = xb;   // xb dead after QKV GEMM; attention output aliases it

  k_cvt_bf16<<<(M_*C_/4 + 255)/256, 256, 0, stream>>>(x, xb, M_*C_);
  dim3 tb(32, 8);
  k_transpose_w<<<dim3(3*C_/32, C_/32), tb, 0, stream>>>(W_qkv, WqkvT, C_, 3*C_);
  k_transpose_w<<<dim3(C_/32,   C_/32), tb, 0, stream>>>(W_proj, WprojT, C_, C_);
  k_rope_tab<<<T_/8, tb, 0, stream>>>(cosT, sinT);

  k_gemm<3*C_, C_, 0><<<dim3(3*C_/128, M_/128), 256, 0, stream>>>(
      xb, WqkvT, b_qkv, cosT, sinT, Qh, Kh, VhT, nullptr);

  k_attn<<<dim3(T_/128, BH_), 256, 0, stream>>>(Qh, Kh, VhT, Y);

  k_gemm<C_, C_, 1><<<dim3(C_/128, M_/128), 256, 0, stream>>>(
      Y, WprojT, b_proj, nullptr, nullptr, nullptr, nullptr, nullptr, out);
}

// Round 5
// 213.031 us; speedup vs baseline: 1.7976x; 1.3157x over previous
//
#include <hip/hip_runtime.h>
#include <stdint.h>

#define B_  4
#define T_  2048
#define C_  1024
#define NH_ 16
#define HD_ 64
#define BH_ (B_*NH_)   // 64
#define M_  (B_*T_)    // 8192

using f32x4  = __attribute__((ext_vector_type(4))) float;
using f32x16 = __attribute__((ext_vector_type(16))) float;
using bf16x8 = __attribute__((ext_vector_type(8))) short;   // 8 bf16 in 4 VGPRs

__device__ __forceinline__ unsigned short f2bf(float x) {
  union { float f; uint32_t u; } v; v.f = x;
  uint32_t u = v.u;
  return (unsigned short)((u + 0x7FFFu + ((u >> 16) & 1u)) >> 16);  // RNE
}

// packed f32x2 -> bf16x2 in one dword (lo=cvt(a), hi=cvt(b))
__device__ __forceinline__ uint32_t cvtpk(float a, float b) {
  uint32_t r;
  asm("v_cvt_pk_bf16_f32 %0, %1, %2" : "=v"(r) : "v"(a), "v"(b));
  return r;
}

// async global->LDS, 16B per lane. lds ptr must be wave-uniform base; HW adds lane*16.
__device__ __forceinline__ void gload16(const void* g, void* l) {
  __builtin_amdgcn_global_load_lds(
      (const __attribute__((address_space(1))) void*)g,
      (__attribute__((address_space(3))) void*)l, 16, 0, 0);
}

// ---------------- prep kernels ----------------

__global__ void k_cvt_bf16(const float* __restrict__ src,
                           unsigned short* __restrict__ dst, int n) {
  int i = (blockIdx.x * 256 + threadIdx.x) * 4;
  if (i + 3 < n) {
    float4 v = *(const float4*)(src + i);
    ushort4 o;
    o.x = f2bf(v.x); o.y = f2bf(v.y); o.z = f2bf(v.z); o.w = f2bf(v.w);
    *(ushort4*)(dst + i) = o;
  }
}

// W [K][N] f32 -> WT [N][K] bf16, 32x32 LDS tile
__global__ void k_transpose_w(const float* __restrict__ W,
                              unsigned short* __restrict__ WT, int K, int N) {
  __shared__ float tile[32][33];
  int bx = blockIdx.x, by = blockIdx.y;
  int tx = threadIdx.x, ty = threadIdx.y;   // (32,8)
  #pragma unroll
  for (int i = 0; i < 32; i += 8)
    tile[ty + i][tx] = W[(size_t)(by*32 + ty + i) * N + bx*32 + tx];
  __syncthreads();
  #pragma unroll
  for (int i = 0; i < 32; i += 8)
    WT[(size_t)(bx*32 + ty + i) * K + by*32 + tx] = f2bf(tile[tx][ty + i]);
}

__global__ void k_rope_tab(float* __restrict__ cosT, float* __restrict__ sinT) {
  int t = blockIdx.x * 8 + threadIdx.y;   // block (32,8)
  int i = threadIdx.x;                    // 0..31
  float inv = expf(-(float)i * (9.210340371976184f / 32.0f));
  float f = (float)t * inv;
  cosT[t*32 + i] = cosf(f);
  sinT[t*32 + i] = sinf(f);
}

// ---------------- GEMM (128x128 tile, BK=64, 4 waves, swizzled LDS) ----------------
template<int N, int K, int EPI>
__global__ __launch_bounds__(256)
void k_gemm(const unsigned short* __restrict__ A,
            const unsigned short* __restrict__ BT,
            const float* __restrict__ bias,
            const float* __restrict__ cosT,
            const float* __restrict__ sinT,
            unsigned short* __restrict__ Qh,
            unsigned short* __restrict__ Kh,
            unsigned short* __restrict__ VhT,
            float* __restrict__ outF) {
  __shared__ alignas(16) unsigned short As[128*64];
  __shared__ alignas(16) unsigned short Bs[128*64];
  const int tid  = threadIdx.x;
  const int lane = tid & 63;
  const int wv   = tid >> 6;
  const int wm   = wv >> 1, wn = wv & 1;
  const int m0   = blockIdx.y * 128;
  const int n0   = blockIdx.x * 128;
  const int l15  = lane & 15, l4 = lane >> 4;

  f32x4 acc[4][4] = {};

  for (int kt = 0; kt < K/64; ++kt) {
    __syncthreads();
    #pragma unroll
    for (int it = 0; it < 4; ++it) {
      int idx  = it*256 + wv*64 + lane;
      int row  = idx >> 3, slot = idx & 7;
      int g    = slot ^ (row & 7);
      const unsigned short* ga = A  + ((size_t)(m0 + row) * K + kt*64 + g*8);
      const unsigned short* gb = BT + ((size_t)(n0 + row) * K + kt*64 + g*8);
      gload16(ga, (void*)(As + (it*256 + wv*64) * 8));
      gload16(gb, (void*)(Bs + (it*256 + wv*64) * 8));
    }
    __syncthreads();
    #pragma unroll
    for (int ks = 0; ks < 2; ++ks) {
      bf16x8 af[4], bfr[4];
      #pragma unroll
      for (int mi = 0; mi < 4; ++mi) {
        int r = wm*64 + mi*16 + l15;
        int g = (ks*4 + l4) ^ (r & 7);
        af[mi] = *(const bf16x8*)(As + r*64 + g*8);
      }
      #pragma unroll
      for (int ni = 0; ni < 4; ++ni) {
        int r = wn*64 + ni*16 + l15;
        int g = (ks*4 + l4) ^ (r & 7);
        bfr[ni] = *(const bf16x8*)(Bs + r*64 + g*8);
      }
      #pragma unroll
      for (int mi = 0; mi < 4; ++mi)
        #pragma unroll
        for (int ni = 0; ni < 4; ++ni)
          acc[mi][ni] = __builtin_amdgcn_mfma_f32_16x16x32_bf16(
              af[mi], bfr[ni], acc[mi][ni], 0, 0, 0);
    }
  }

  if (EPI == 0) {
    const int ncol = n0 + wn*64;            // wave spans exactly one (part, head)
    const int part = ncol >> 10;            // 0=Q 1=K 2=V
    const int hid  = (ncol & 1023) >> 6;
    unsigned short* dstQK = (part == 0) ? Qh : Kh;
    #pragma unroll
    for (int mi = 0; mi < 4; ++mi) {
      #pragma unroll
      for (int j = 0; j < 4; ++j) {
        int row = m0 + wm*64 + mi*16 + l4*4 + j;
        int bb = row >> 11, tt = row & 2047;
        if (part < 2) {
          size_t base = ((size_t)((bb*NH_ + hid) * T_ + tt)) * HD_;
          #pragma unroll
          for (int ni = 0; ni < 2; ++ni) {
            int d = ni*16 + l15;
            float a1 = acc[mi][ni][j]     + bias[ncol + d];
            float a2 = acc[mi][ni + 2][j] + bias[ncol + d + 32];
            float cv = cosT[tt*32 + d], sv = sinT[tt*32 + d];
            float o1 = a1*cv - a2*sv;
            float o2 = a2*cv + a1*sv;
            // Q: fold 1/sqrt(64) * log2(e) so attention works in exp2 domain
            if (part == 0) { o1 *= 0.18033688011112042f; o2 *= 0.18033688011112042f; }
            dstQK[base + d]      = f2bf(o1);
            dstQK[base + d + 32] = f2bf(o2);
          }
        } else {
          #pragma unroll
          for (int ni = 0; ni < 4; ++ni) {
            int d = ni*16 + l15;
            float av = acc[mi][ni][j] + bias[ncol + d];
            VhT[((size_t)((bb*NH_ + hid) * HD_ + d)) * T_ + tt] = f2bf(av);
          }
        }
      }
    }
  } else {
    #pragma unroll
    for (int mi = 0; mi < 4; ++mi)
      #pragma unroll
      for (int ni = 0; ni < 4; ++ni)
        #pragma unroll
        for (int j = 0; j < 4; ++j) {
          int row = m0 + wm*64 + mi*16 + l4*4 + j;
          int col = n0 + wn*64 + ni*16 + l15;
          outF[(size_t)row * N + col] = acc[mi][ni][j] + bias[col];
        }
  }
}

// ---------------- flash attention (causal), 32x32 MFMA, swapped QK^T ----------------
// Qh: pre-scaled by 0.125*log2(e) -> scores in log2 domain, softmax via exp2.
// 1D grid: bh = blk&63, qb = 15-(blk>>6)  => per-CU qb spread (load balance).
// Lane l owns q-row (l&31); S^T via mfma(K,Q); PV via mfma(V^T,P) => q lane-local.
__global__ __launch_bounds__(256, 3)
void k_attn(const unsigned short* __restrict__ Qh,
            const unsigned short* __restrict__ Kh,
            const unsigned short* __restrict__ VhT,
            unsigned short* __restrict__ Y) {
  __shared__ alignas(16) unsigned short Ks[2][64*64];   // [key][d], XOR-swizzled 16B granules
  __shared__ alignas(16) unsigned short Vs[2][64*64];   // [d][key], XOR-swizzled
  const int tid  = threadIdx.x;
  const int lane = tid & 63;
  const int wv   = tid >> 6;
  const int l31  = lane & 31;
  const int h    = lane >> 5;
  const int bh   = blockIdx.x & 63;
  const int qb   = 15 - (blockIdx.x >> 6);          // balanced qb spread per CU
  const int r32  = qb*128 + wv*32;                  // wave's first q-row
  const int nt   = 2*qb + 2;
  const int qg   = r32 + l31;                       // this lane's q-row (global)

  // Q B-frags: qf[i] = Q[qg][d = i*16 + h*8 + e]
  bf16x8 qf[4];
  #pragma unroll
  for (int i = 0; i < 4; ++i)
    qf[i] = *(const bf16x8*)(Qh + ((size_t)(bh*T_ + qg))*HD_ + i*16 + h*8);

  float m_r = -1e30f, l_r = 0.f;
  f32x16 o[2] = {};   // o[dblk][r]: O[q = qg][d = dblk*32 + (r&3)+8*(r>>2)+4*h]

  auto stage = [&](int buf, int jt) {
    #pragma unroll
    for (int it = 0; it < 2; ++it) {
      int idx = it*256 + wv*64 + lane;
      int row = idx >> 3, slot = idx & 7;
      int g   = slot ^ (row & 7);
      gload16(Kh  + ((size_t)(bh*T_ + jt*64 + row))*HD_ + g*8,
              (void*)(Ks[buf] + (it*256 + wv*64)*8));
      gload16(VhT + ((size_t)(bh*HD_ + row))*T_ + jt*64 + g*8,
              (void*)(Vs[buf] + (it*256 + wv*64)*8));
    }
  };

  stage(0, 0);
  int cur = 0;

  for (int jt = 0; jt < nt; ++jt) {
    if (jt + 1 < nt) {
      stage(cur ^ 1, jt + 1);
      asm volatile("s_waitcnt vmcnt(4)" ::: "memory");
    } else {
      asm volatile("s_waitcnt vmcnt(0)" ::: "memory");
    }
    __builtin_amdgcn_s_barrier();
    asm volatile("" ::: "memory");

    if (jt*64 <= r32 + 31) {     // wave-uniform skip of fully-masked tiles
      // S^T tiles: s[kb][r] = S[key = jt*64+kb*32+(r&3)+8*(r>>2)+4*h][q = qg]
      f32x16 s[2] = {f32x16{0}, f32x16{0}};
      __builtin_amdgcn_s_setprio(1);
      #pragma unroll
      for (int kb = 0; kb < 2; ++kb)
        #pragma unroll
        for (int i = 0; i < 4; ++i) {
          int r = kb*32 + l31;
          int g = (2*i + h) ^ (r & 7);
          bf16x8 kf = *(const bf16x8*)(Ks[cur] + r*64 + g*8);
          s[kb] = __builtin_amdgcn_mfma_f32_32x32x16_bf16(kf, qf[i], s[kb], 0, 0, 0);
        }
      __builtin_amdgcn_s_setprio(0);

      // extract + causal mask (diagonal tiles only)
      float p[2][16];
      const bool diag = (jt + 1)*64 > r32;
      #pragma unroll
      for (int kb = 0; kb < 2; ++kb)
        #pragma unroll
        for (int r = 0; r < 16; ++r) {
          float v = s[kb][r];
          if (diag) {
            int key = jt*64 + kb*32 + (r & 3) + 8*(r >> 2) + 4*h;
            v = (key > qg) ? -1e30f : v;
          }
          p[kb][r] = v;
        }

      // row max: in-lane tree + one cross-half swap
      float mx[16];
      #pragma unroll
      for (int r = 0; r < 16; ++r) mx[r] = fmaxf(p[0][r], p[1][r]);
      #pragma unroll
      for (int st = 8; st > 0; st >>= 1)
        #pragma unroll
        for (int r = 0; r < 8; ++r)
          if (r < st) mx[r] = fmaxf(mx[r], mx[r + st]);
      float tm = fmaxf(mx[0], __shfl_xor(mx[0], 32));

      // defer-max (T13): only rescale when tile max outgrows running max by >8
      if (!__all(tm <= m_r + 8.0f)) {
        float mn = fmaxf(m_r, tm);
        float scale = exp2f(m_r - mn);
        m_r = mn;
        l_r *= scale;
        #pragma unroll
        for (int dblk = 0; dblk < 2; ++dblk)
          #pragma unroll
          for (int r = 0; r < 16; ++r)
            o[dblk][r] *= scale;
      }

      #pragma unroll
      for (int kb = 0; kb < 2; ++kb)
        #pragma unroll
        for (int r = 0; r < 16; ++r)
          p[kb][r] = exp2f(p[kb][r] - m_r);

      float sm[16];
      #pragma unroll
      for (int r = 0; r < 16; ++r) sm[r] = p[0][r] + p[1][r];
      #pragma unroll
      for (int st = 8; st > 0; st >>= 1)
        #pragma unroll
        for (int r = 0; r < 8; ++r)
          if (r < st) sm[r] += sm[r + st];
      l_r += sm[0] + __shfl_xor(sm[0], 32);

      // PV per key-block: P B-frags via cvt_pk + ONE swap per pair (pre-selected).
      // h=0 needs partner's (p0..p3)-words; h=1 needs partner's (p4..p7)-words.
      #pragma unroll
      for (int kb = 0; kb < 2; ++kb) {
        uint32_t a01 = cvtpk(p[kb][0],  p[kb][1]);
        uint32_t a23 = cvtpk(p[kb][2],  p[kb][3]);
        uint32_t a45 = cvtpk(p[kb][4],  p[kb][5]);
        uint32_t a67 = cvtpk(p[kb][6],  p[kb][7]);
        uint32_t b01 = cvtpk(p[kb][8],  p[kb][9]);
        uint32_t b23 = cvtpk(p[kb][10], p[kb][11]);
        uint32_t b45 = cvtpk(p[kb][12], p[kb][13]);
        uint32_t b67 = cvtpk(p[kb][14], p[kb][15]);
        uint32_t s1 = h ? a01 : a45, s2 = h ? a23 : a67;   // send what partner needs
        uint32_t s3 = h ? b01 : b45, s4 = h ? b23 : b67;
        uint32_t x1 = __shfl_xor(s1, 32), x2 = __shfl_xor(s2, 32);
        uint32_t x3 = __shfl_xor(s3, 32), x4 = __shfl_xor(s4, 32);
        union { bf16x8 v; uint32_t d[4]; } f0, f1;
        f0.d[0] = h ? x1 : a01;  f0.d[1] = h ? x2 : a23;
        f0.d[2] = h ? a45 : x1;  f0.d[3] = h ? a67 : x2;
        f1.d[0] = h ? x3 : b01;  f1.d[1] = h ? x4 : b23;
        f1.d[2] = h ? b45 : x3;  f1.d[3] = h ? b67 : x4;

        __builtin_amdgcn_s_setprio(1);
        #pragma unroll
        for (int koff = 0; koff < 2; ++koff) {
          bf16x8 pf = koff ? f1.v : f0.v;
          #pragma unroll
          for (int dblk = 0; dblk < 2; ++dblk) {
            int rv = dblk*32 + l31;
            int gv = (kb*4 + koff*2 + h) ^ (rv & 7);
            bf16x8 vf = *(const bf16x8*)(Vs[cur] + rv*64 + gv*8);
            // A = V^T (row=d, lane-local l31), B = P (col=q, lane-local l31)
            o[dblk] = __builtin_amdgcn_mfma_f32_32x32x16_bf16(vf, pf, o[dblk], 0, 0, 0);
          }
        }
        __builtin_amdgcn_s_setprio(0);
      }
    }

    __syncthreads();
    cur ^= 1;
  }

  // epilogue: lane-local normalize, packed ushort4 stores
  // o[dblk][g2*4+j] -> d = dblk*32 + 8*g2 + 4*h + j  (4 consecutive d per reg-quad)
  int b = bh >> 4, hd = bh & 15;
  float rinv = 1.0f / l_r;
  unsigned short* yrow = Y + ((size_t)(b*T_ + r32 + l31))*C_ + hd*64;
  #pragma unroll
  for (int dblk = 0; dblk < 2; ++dblk)
    #pragma unroll
    for (int g2 = 0; g2 < 4; ++g2) {
      ushort4 o4;
      o4.x = f2bf(o[dblk][g2*4 + 0] * rinv);
      o4.y = f2bf(o[dblk][g2*4 + 1] * rinv);
      o4.z = f2bf(o[dblk][g2*4 + 2] * rinv);
      o4.w = f2bf(o[dblk][g2*4 + 3] * rinv);
      *(ushort4*)(yrow + dblk*32 + g2*8 + 4*h) = o4;
    }
}

// ---------------- host ----------------

extern "C" void kernel_launch(void* const* d_in, const int* in_sizes, int n_in,
                              void* d_out, int out_size, void* d_ws, size_t ws_size,
                              hipStream_t stream) {
  const float* x      = (const float*)d_in[0];
  const float* W_qkv  = (const float*)d_in[1];
  const float* b_qkv  = (const float*)d_in[2];
  const float* W_proj = (const float*)d_in[3];
  const float* b_proj = (const float*)d_in[4];
  float* out = (float*)d_out;

  char* ws = (char*)d_ws;
  size_t off = 0;
  auto alloc = [&](size_t bytes) {
    void* p = ws + off; off += (bytes + 255) & ~(size_t)255; return p;
  };
  unsigned short* xb     = (unsigned short*)alloc((size_t)M_ * C_ * 2);  // also reused as Y
  unsigned short* WqkvT  = (unsigned short*)alloc((size_t)3 * C_ * C_ * 2);
  unsigned short* WprojT = (unsigned short*)alloc((size_t)C_ * C_ * 2);
  unsigned short* Qh     = (unsigned short*)alloc((size_t)M_ * C_ * 2);
  unsigned short* Kh     = (unsigned short*)alloc((size_t)M_ * C_ * 2);
  unsigned short* VhT    = (unsigned short*)alloc((size_t)M_ * C_ * 2);
  float* cosT = (float*)alloc((size_t)T_ * 32 * 4);
  float* sinT = (float*)alloc((size_t)T_ * 32 * 4);
  unsigned short* Y = xb;   // xb dead after QKV GEMM; attention output aliases it

  k_cvt_bf16<<<(M_*C_/4 + 255)/256, 256, 0, stream>>>(x, xb, M_*C_);
  dim3 tb(32, 8);
  k_transpose_w<<<dim3(3*C_/32, C_/32), tb, 0, stream>>>(W_qkv, WqkvT, C_, 3*C_);
  k_transpose_w<<<dim3(C_/32,   C_/32), tb, 0, stream>>>(W_proj, WprojT, C_, C_);
  k_rope_tab<<<T_/8, tb, 0, stream>>>(cosT, sinT);

  k_gemm<3*C_, C_, 0><<<dim3(3*C_/128, M_/128), 256, 0, stream>>>(
      xb, WqkvT, b_qkv, cosT, sinT, Qh, Kh, VhT, nullptr);

  k_attn<<<dim3(T_/128 * BH_), 256, 0, stream>>>(Qh, Kh, VhT, Y);

  k_gemm<C_, C_, 1><<<dim3(C_/128, M_/128), 256, 0, stream>>>(
      Y, WprojT, b_proj, nullptr, nullptr, nullptr, nullptr, nullptr, out);
}